// Round 7
// baseline (298.780 us; speedup 1.0000x reference)
//
#include <hip/hip_runtime.h>
#include <hip/hip_bf16.h>
#include <stdint.h>

// Problem constants (fixed by setup_inputs)
#define NE   8
#define DOUT 2048
#define DIN  2048
#define SEQ  8192
#define GSZ  128
#define FP8_MAX 448.0f
#define EPSQ 1e-12f

typedef float f32x4  __attribute__((ext_vector_type(4)));
typedef float f32x16 __attribute__((ext_vector_type(16)));
typedef int   i32x4  __attribute__((ext_vector_type(4)));
typedef int   i32x8  __attribute__((ext_vector_type(8)));

// async global->LDS, 16B/lane. LDS dest = wave-uniform base (+lane*16 by HW);
// global src may be per-lane.
__device__ __forceinline__ void async16(void* lds_base, const void* gptr) {
    __builtin_amdgcn_global_load_lds(
        (const __attribute__((address_space(1))) unsigned int*)gptr,
        (__attribute__((address_space(3))) unsigned int*)lds_base,
        16, 0, 0);
}

// ---------------------------------------------------------------------------
// Kernel 1: per-1x128-tile quant of x. One float4 per thread; each 32-lane
// half-wave group covers one tile. Coalesced float4 loads, dword stores.
__global__ __launch_bounds__(256) void quant_x_kernel(
    const float* __restrict__ x, unsigned char* __restrict__ qx,
    float* __restrict__ sx)
{
    const int g = blockIdx.x * 256 + threadIdx.x;   // float4 group index
    const float4 v = ((const float4*)x)[g];
    float a = fmaxf(fmaxf(fabsf(v.x), fabsf(v.y)),
                    fmaxf(fabsf(v.z), fabsf(v.w)));
    #pragma unroll
    for (int o = 16; o; o >>= 1) a = fmaxf(a, __shfl_xor(a, o));  // 32-lane tile
    const float scale = fmaxf(a, EPSQ) / FP8_MAX;
    const int tile = g >> 5;                        // == row*16 + kb
    if ((threadIdx.x & 31) == 0) sx[tile] = scale;

    float q0 = fminf(fmaxf(v.x / scale, -FP8_MAX), FP8_MAX);
    float q1 = fminf(fmaxf(v.y / scale, -FP8_MAX), FP8_MAX);
    float q2 = fminf(fmaxf(v.z / scale, -FP8_MAX), FP8_MAX);
    float q3 = fminf(fmaxf(v.w / scale, -FP8_MAX), FP8_MAX);
    int lo = __builtin_amdgcn_cvt_pk_fp8_f32(q0, q1, 0, false);
    int pk = __builtin_amdgcn_cvt_pk_fp8_f32(q2, q3, lo, true);
    ((unsigned int*)qx)[g] = (unsigned int)pk;
}

// ---------------------------------------------------------------------------
// Kernel 2 (v2): per-128x128-block quant of w, LDS-FREE. 512 threads; each
// thread holds its 8 float4 in registers (single global read of w), amax
// reduced in-reg -> wave shfl -> 8-entry LDS, quantize from registers.
// vs v1 (64 KB LDS, 2 blocks/CU latency-capped): 32 waves/CU, 8-deep load
// ILP, no LDS staging round-trip. Identical math -> identical qw bytes.
__global__ __launch_bounds__(512) void quant_w_kernel(
    const float* __restrict__ w, unsigned char* __restrict__ qw,
    float* __restrict__ sw)
{
    __shared__ float red[8];

    const int cb = blockIdx.x;   // din block 0..15
    const int rb = blockIdx.y;   // dout block 0..15
    const int e  = blockIdx.z;   // expert 0..7
    const int t  = threadIdx.x;
    const int lane = t & 63, wv = t >> 6;

    const size_t base = ((size_t)e * DOUT + rb * GSZ) * DIN + cb * GSZ;
    const float* wp = w + base;

    // thread t covers f32x4 index idx = t + i*512 (i<8): row = idx>>5, c4 = idx&31
    f32x4 v[8];
    #pragma unroll
    for (int i = 0; i < 8; ++i) {
        int idx = t + i * 512;
        int row = idx >> 5, c4 = idx & 31;
        v[i] = *(const f32x4*)(wp + (size_t)row * DIN + c4 * 4);
    }

    float a = 0.f;
    #pragma unroll
    for (int i = 0; i < 8; ++i)
        a = fmaxf(a, fmaxf(fmaxf(fabsf(v[i][0]), fabsf(v[i][1])),
                           fmaxf(fabsf(v[i][2]), fabsf(v[i][3]))));
    #pragma unroll
    for (int o = 32; o; o >>= 1) a = fmaxf(a, __shfl_xor(a, o));
    if (lane == 0) red[wv] = a;
    __syncthreads();
    a = red[0];
    #pragma unroll
    for (int i = 1; i < 8; ++i) a = fmaxf(a, red[i]);
    const float scale = fmaxf(a, EPSQ) / FP8_MAX;
    if (t == 0) sw[(e * 16 + rb) * 16 + cb] = scale;

    unsigned int* qout = (unsigned int*)(qw + base);
    #pragma unroll
    for (int i = 0; i < 8; ++i) {
        int idx = t + i * 512;
        float q0 = fminf(fmaxf(v[i][0] / scale, -FP8_MAX), FP8_MAX);
        float q1 = fminf(fmaxf(v[i][1] / scale, -FP8_MAX), FP8_MAX);
        float q2 = fminf(fmaxf(v[i][2] / scale, -FP8_MAX), FP8_MAX);
        float q3 = fminf(fmaxf(v[i][3] / scale, -FP8_MAX), FP8_MAX);
        int lo = __builtin_amdgcn_cvt_pk_fp8_f32(q0, q1, 0, false);
        int pk = __builtin_amdgcn_cvt_pk_fp8_f32(q2, q3, lo, true);
        int row = idx >> 5, c4 = idx & 31;
        qout[row * (DIN / 4) + c4] = (unsigned int)pk;
    }
}

// ---------------------------------------------------------------------------
// Kernel 3: grouped fp8 GEMM, 256x128 tile (BMxBN), 8 waves (4M x 2N, each
// wave 64x64 out), single-buffered 2-barrier K-loop, MX-scaled MFMA 32x32x64
// fp8 (unit e8m0 scales). 64 KB LDS -> 2 blocks/CU (16 waves/CU).
//
// r7 change: the accumulator rescale (RsC reads + VALU) is moved BETWEEN the
// staging-load issue and the barrier. It depends on nothing staged, so it
// executes under the global_load_lds latency that was previously fully
// exposed at the compiler-emitted "s_waitcnt vmcnt(0)" before s_barrier.
// Float sequence unchanged: rescale(kb) still precedes MFMA(kb).
//
// Telescoped per-128-k-block rescale with COMBINED row x col table (BN=128
// spans a single weight-scale column):
//   c[s,j] = sx[s,j] * sw[e,nb,j]
//   A_j = A_{j-1} * RsC[j][s] + P_j ;  out = A_15 * RsC[0][s]
//   RsC[j][s] = c[s,j-1]/c[s,j]  (j>0),  RsC[0][s] = c[s,15]
// LDS tiles XOR-swizzled on 16B chunks (pos = chunk ^ (row&7)); a lane's 32B
// fragment = two ds_read_b128 at chunk c = ks*4 + (lane>>5)*2 + {0,1}.
// 32x32 C/D layout: col = lane&31, row = (reg&3) + 8*(reg>>2) + 4*(lane>>5).
// A/B fragment: row = lane&31, k = (lane>>5)*32 + byte.
__global__ __launch_bounds__(512, 4) void gemm_kernel(
    const unsigned char* __restrict__ qx, const float* __restrict__ sx,
    const unsigned char* __restrict__ qw, const float* __restrict__ sw,
    const int* __restrict__ tpe, float* __restrict__ out)
{
    __shared__ __align__(16) unsigned char Asm[256 * 128];  // 32 KB
    __shared__ __align__(16) unsigned char Bsm[128 * 128];  // 16 KB
    __shared__ __align__(16) float RsC[16 * 256];           // 16 KB [kb][row]

    const int tid  = threadIdx.x;
    const int lane = tid & 63;
    const int wv   = tid >> 6;          // 0..7
    const int wm   = wv >> 1;           // 0..3  (M quarter: 64 rows)
    const int wn   = wv & 1;            // 0..1  (N half: 64 cols)
    const int l31  = lane & 31;
    const int h    = lane >> 5;
    const int nb   = blockIdx.x;        // 0..15 (128-col block)
    const int mb   = blockIdx.y;        // 0..31 (256-row block)
    const int r0   = mb * 256, n0 = nb * 128;

    int e = -1, start = 0;
    #pragma unroll
    for (int i = 0; i < NE; ++i) {
        int end = start + tpe[i];
        if (r0 >= start && r0 < end) e = i;
        start = end;
    }
    if (e < 0) {
        f32x4 z = {0.f, 0.f, 0.f, 0.f};
        for (int i = tid; i < 256 * 32; i += 512) {
            int r = i >> 5, c4 = i & 31;
            *(f32x4*)(out + (size_t)(r0 + r) * DOUT + n0 + c4 * 4) = z;
        }
        return;
    }

    // ---- prologue: combined c = sx*sw into Asm scratch, ratios into RsC ----
    {
        float* Cs = (float*)Asm;              // 16 KB scratch inside A tile
        const float* sp  = sx + (size_t)r0 * 16;
        const float* swp = sw + (e * 16 + nb) * 16;
        for (int i = tid; i < 4096; i += 512) {
            int row = i >> 4, kb = i & 15;    // i == row*16 + kb
            Cs[kb * 256 + row] = sp[i] * swp[kb];
        }
        __syncthreads();
        float rv[8];
        #pragma unroll
        for (int j = 0; j < 8; ++j) {
            int i = tid + j * 512;
            int kb = i >> 8, row = i & 255;
            rv[j] = (kb == 0) ? Cs[15 * 256 + row]
                              : Cs[(kb - 1) * 256 + row] / Cs[kb * 256 + row];
        }
        #pragma unroll
        for (int j = 0; j < 8; ++j) RsC[tid + j * 512] = rv[j];
        // loop-top __syncthreads() orders: Cs reads done before Asm staging,
        // RsC writes visible before first rescale use (kb=1).
    }

    const unsigned char* Ag = qx + (size_t)r0 * DIN;
    const unsigned char* Bg = qw + (size_t)e * DOUT * DIN + (size_t)n0 * DIN;

    // staging source indices (per-lane, loop-invariant)
    // A: wave stages 4 KB (rows wv*32..): j=0..3 ; B: 2 KB: j=0..1
    int sa_off[4], sa_dst[4], sb_off[2], sb_dst[2];
    #pragma unroll
    for (int j = 0; j < 4; ++j) {
        int f = wv * 4096 + j * 1024 + lane * 16;   // byte index in 32 KB tile
        int row = f >> 7, pc = (f >> 4) & 7;
        sa_off[j] = row * DIN + ((pc ^ (row & 7)) * 16);
        sa_dst[j] = wv * 4096 + j * 1024;
    }
    #pragma unroll
    for (int j = 0; j < 2; ++j) {
        int f = wv * 2048 + j * 1024 + lane * 16;   // byte index in 16 KB tile
        int row = f >> 7, pc = (f >> 4) & 7;
        sb_off[j] = row * DIN + ((pc ^ (row & 7)) * 16);
        sb_dst[j] = wv * 2048 + j * 1024;
    }

    // fragment read bases (A row = wm*64+mi*32+l31, B row = wn*64+ni*32+l31)
    int abase[2], ax8[2], bbase[2], bx8[2];
    #pragma unroll
    for (int i = 0; i < 2; ++i) {
        int ra = wm * 64 + i * 32 + l31;
        abase[i] = ra * 128; ax8[i] = ra & 7;
        int rb = wn * 64 + i * 32 + l31;
        bbase[i] = rb * 128; bx8[i] = rb & 7;
    }

    f32x16 acc[2][2];
    #pragma unroll
    for (int mi = 0; mi < 2; ++mi)
        #pragma unroll
        for (int ni = 0; ni < 2; ++ni)
            #pragma unroll
            for (int q = 0; q < 16; ++q) acc[mi][ni][q] = 0.f;

    for (int kb = 0; kb < 16; ++kb) {
        __syncthreads();   // frag reads of kb-1 done by all waves
        // issue staging for kb (async; latency hidden under rescale below)
        #pragma unroll
        for (int j = 0; j < 4; ++j)
            async16(Asm + sa_dst[j], Ag + (size_t)sa_off[j] + kb * GSZ);
        #pragma unroll
        for (int j = 0; j < 2; ++j)
            async16(Bsm + sb_dst[j], Bg + (size_t)sb_off[j] + kb * GSZ);

        if (kb) {   // rescale accumulators (independent of staged data)
            #pragma unroll
            for (int mi = 0; mi < 2; ++mi) {
                const float* rp = RsC + kb * 256 + wm * 64 + mi * 32 + 4 * h;
                f32x4 rr[4];
                #pragma unroll
                for (int g = 0; g < 4; ++g) rr[g] = *(const f32x4*)(rp + 8 * g);
                #pragma unroll
                for (int ni = 0; ni < 2; ++ni)
                    #pragma unroll
                    for (int g = 0; g < 4; ++g)
                        #pragma unroll
                        for (int j = 0; j < 4; ++j)
                            acc[mi][ni][g * 4 + j] *= rr[g][j];
            }
        }
        __syncthreads();   // staged data visible (vmcnt drain lands here)

        #pragma unroll
        for (int ks = 0; ks < 2; ++ks) {
            const int c0 = ks * 4 + h * 2;
            i32x8 Bk[2];
            #pragma unroll
            for (int ni = 0; ni < 2; ++ni) {
                i32x4 lo = *(const i32x4*)(Bsm + bbase[ni] + (((c0    ) ^ bx8[ni]) * 16));
                i32x4 hi = *(const i32x4*)(Bsm + bbase[ni] + (((c0 + 1) ^ bx8[ni]) * 16));
                #pragma unroll
                for (int q = 0; q < 4; ++q) { Bk[ni][q] = lo[q]; Bk[ni][q + 4] = hi[q]; }
            }
            #pragma unroll
            for (int mi = 0; mi < 2; ++mi) {
                i32x8 Af;
                i32x4 alo = *(const i32x4*)(Asm + abase[mi] + (((c0    ) ^ ax8[mi]) * 16));
                i32x4 ahi = *(const i32x4*)(Asm + abase[mi] + (((c0 + 1) ^ ax8[mi]) * 16));
                #pragma unroll
                for (int q = 0; q < 4; ++q) { Af[q] = alo[q]; Af[q + 4] = ahi[q]; }
                #pragma unroll
                for (int ni = 0; ni < 2; ++ni)
                    acc[mi][ni] = __builtin_amdgcn_mfma_scale_f32_32x32x64_f8f6f4(
                        Af, Bk[ni], acc[mi][ni],
                        0, 0,                       // cbsz=fp8, blgp=fp8
                        0, 0x7f7f7f7f,              // A scale: e8m0 1.0
                        0, 0x7f7f7f7f);             // B scale: e8m0 1.0
            }
        }
    }

    // epilogue: apply final scale (RsC kb=0 slot).
    // C/D: col = l31, row = (reg&3) + 8*(reg>>2) + 4*h
    #pragma unroll
    for (int mi = 0; mi < 2; ++mi) {
        const float* fp = RsC + wm * 64 + mi * 32 + 4 * h;
        f32x4 fv[4];
        #pragma unroll
        for (int g = 0; g < 4; ++g) fv[g] = *(const f32x4*)(fp + 8 * g);
        const int rbase = r0 + wm * 64 + mi * 32 + 4 * h;
        #pragma unroll
        for (int ni = 0; ni < 2; ++ni) {
            const int col = n0 + wn * 64 + ni * 32 + l31;
            #pragma unroll
            for (int g = 0; g < 4; ++g)
                #pragma unroll
                for (int j = 0; j < 4; ++j)
                    out[(size_t)(rbase + 8 * g + j) * DOUT + col] =
                        acc[mi][ni][g * 4 + j] * fv[g][j];
        }
    }
}

// ---------------------------------------------------------------------------
extern "C" void kernel_launch(void* const* d_in, const int* in_sizes, int n_in,
                              void* d_out, int out_size, void* d_ws, size_t ws_size,
                              hipStream_t stream) {
    const float* x   = (const float*)d_in[0];   // [8192, 2048] fp32
    const float* wt  = (const float*)d_in[1];   // [16384, 2048] fp32
    const int*   tpe = (const int*)d_in[2];     // [8]
    float* out = (float*)d_out;                 // [8192, 2048] fp32

    char* ws = (char*)d_ws;
    unsigned char* qx = (unsigned char*)ws;                       // 16 MB
    unsigned char* qw = qx + (size_t)SEQ * DIN;                   // 32 MB
    float* sx = (float*)(qw + (size_t)NE * DOUT * DIN);           // 512 KB
    float* sw = sx + (size_t)SEQ * 16;                            // 4 KB

    quant_x_kernel<<<SEQ * DIN / 4 / 256, 256, 0, stream>>>(x, qx, sx);
    quant_w_kernel<<<dim3(16, 16, NE), 512, 0, stream>>>(wt, qw, sw);
    gemm_kernel<<<dim3(DOUT / 128, SEQ / 256), 512, 0, stream>>>(
        qx, sx, qw, sw, tpe, out);
}